// Round 7
// baseline (601.604 us; speedup 1.0000x reference)
//
#include <hip/hip_runtime.h>

// Pose_Loss: B=65536 rows, D=154 cols, 4 fp32 arrays + 2 int mask arrays.
// out[0] = (dot(use_l, rowsum(recon_l)) + dot(use_r, rowsum(recon_r))) / 154
// out[1] =  dot(use_l, rowsum(KLD_l))   + dot(use_r, rowsum(KLD_r))
// out[2] =  sum(use_l) + sum(use_r)   (integer count, stored as float)
//
// R7 = R6 (nt loads confirmed: main kernel 56.5 -> <39.5 us) + tail trim:
//  - count via __ballot/popcll (blocks 0..255 only) instead of 6 shuffle
//    rounds in every block;
//  - last-block-done reduction (ticket counter in ws, __threadfence
//    release/acquire) replaces the separate final_reduce launch. Partials
//    are pushed to the coherent LLC by the fence; the reading block holds
//    no stale L2 copies (ws was rewritten by the harness fill dispatch).
//  - main loop unchanged: 1 float4 chunk/thread, 9856 blocks, VGPR ~16,
//    nt loads so HBM-miss fetches don't evict the restore's dirty L3 lines.

#define BB 65536
#define DD 154
#define N4 (BB * DD / 4)        // 2,523,136
#define BLOCKS 9856             // N4 / 256
#define THREADS 256
#define CNT_BLOCKS (BB / THREADS)  // 256 blocks own the count rows

typedef float nt_float4 __attribute__((ext_vector_type(4)));

__global__ void init_ws_kernel(unsigned int* __restrict__ counter) {
    if (threadIdx.x == 0) *counter = 0u;
}

__global__ void zero_out_kernel(float* __restrict__ out) {
    if (threadIdx.x < 3) out[threadIdx.x] = 0.0f;
}

__device__ __forceinline__ float2 wpair(int l, int f) {
    const bool valid = (f != -1);
    float2 w;
    w.x = (valid && ((l == 0) || (l == 2))) ? 1.0f : 0.0f;
    w.y = (valid && ((l == 1) || (l == 2))) ? 1.0f : 0.0f;
    return w;
}

// ws layout: [0..BLOCKS) recon, [B..2B) kld, [2B..3B) cnt, [3B] ticket (uint)
__global__ __launch_bounds__(THREADS) void pose_partial_kernel(
    const float* __restrict__ recon_l, const float* __restrict__ recon_r,
    const float* __restrict__ kld_l,   const float* __restrict__ kld_r,
    const int* __restrict__ lr,        const int* __restrict__ fp,
    float* __restrict__ ws,            unsigned int* __restrict__ counter,
    float* __restrict__ out)
{
    const nt_float4* __restrict__ rl4 = (const nt_float4*)recon_l;
    const nt_float4* __restrict__ rr4 = (const nt_float4*)recon_r;
    const nt_float4* __restrict__ kl4 = (const nt_float4*)kld_l;
    const nt_float4* __restrict__ kr4 = (const nt_float4*)kld_r;

    const int i = blockIdx.x * THREADS + threadIdx.x;   // float4 chunk index
    const int h = 2 * i;
    const int r0 = h / 77;            // row of elements 4i, 4i+1
    const int r1 = (h + 1) / 77;      // row of elements 4i+2, 4i+3

    // non-temporal streaming loads: read once, do not allocate in cache
    const nt_float4 a = __builtin_nontemporal_load(&rl4[i]);
    const nt_float4 b = __builtin_nontemporal_load(&rr4[i]);
    const nt_float4 c = __builtin_nontemporal_load(&kl4[i]);
    const nt_float4 d = __builtin_nontemporal_load(&kr4[i]);

    // weight lookups stay cached (tiny, heavily reused across lanes)
    const float2 w0 = wpair(lr[r0], fp[r0]);
    const float2 w1 = wpair(lr[r1], fp[r1]);

    float acc_recon = w0.x * (a.x + a.y) + w1.x * (a.z + a.w)
                    + w0.y * (b.x + b.y) + w1.y * (b.z + b.w);
    float acc_kld   = w0.x * (c.x + c.y) + w1.x * (c.z + c.w)
                    + w0.y * (d.x + d.y) + w1.y * (d.z + d.w);

    // mask count via ballot: exact small-int popcount, no shuffle rounds.
    // Uniform per-block branch: only blocks 0..255 own count rows (i < BB).
    float n_wave = 0.0f;
    if (blockIdx.x < CNT_BLOCKS) {
        const float2 w = wpair(lr[i], fp[i]);
        n_wave = (float)(__popcll(__ballot(w.x != 0.0f)) +
                         __popcll(__ballot(w.y != 0.0f)));
    }

#pragma unroll
    for (int off = 32; off > 0; off >>= 1) {
        acc_recon += __shfl_down(acc_recon, off, 64);
        acc_kld   += __shfl_down(acc_kld,   off, 64);
    }

    __shared__ float s_r[4], s_k[4], s_n[4];
    __shared__ int s_last;
    const int wave = threadIdx.x >> 6;
    const int lane = threadIdx.x & 63;
    if (lane == 0) {
        s_r[wave] = acc_recon;
        s_k[wave] = acc_kld;
        s_n[wave] = n_wave;
    }
    __syncthreads();

    if (ws != nullptr) {
        if (threadIdx.x == 0) {
            ws[blockIdx.x]              = s_r[0] + s_r[1] + s_r[2] + s_r[3];
            ws[BLOCKS + blockIdx.x]     = s_k[0] + s_k[1] + s_k[2] + s_k[3];
            ws[2 * BLOCKS + blockIdx.x] = s_n[0] + s_n[1] + s_n[2] + s_n[3];
            __threadfence();                       // release partials to LLC
            const unsigned int t = atomicAdd(counter, 1u);
            s_last = (t == BLOCKS - 1u);
        }
        __syncthreads();
        if (s_last) {
            __threadfence();                       // acquire
            const float4* __restrict__ p0 = (const float4*)ws;
            const float4* __restrict__ p1 = (const float4*)(ws + BLOCKS);
            const float4* __restrict__ p2 = (const float4*)(ws + 2 * BLOCKS);
            float r = 0.0f, k = 0.0f, n = 0.0f;
            for (int j = threadIdx.x; j < BLOCKS / 4; j += THREADS) {
                const float4 v0 = p0[j]; r += v0.x + v0.y + v0.z + v0.w;
                const float4 v1 = p1[j]; k += v1.x + v1.y + v1.z + v1.w;
                const float4 v2 = p2[j]; n += v2.x + v2.y + v2.z + v2.w;
            }
#pragma unroll
            for (int off = 32; off > 0; off >>= 1) {
                r += __shfl_down(r, off, 64);
                k += __shfl_down(k, off, 64);
                n += __shfl_down(n, off, 64);
            }
            if (lane == 0) { s_r[wave] = r; s_k[wave] = k; s_n[wave] = n; }
            __syncthreads();
            if (threadIdx.x == 0) {
                out[0] = (s_r[0] + s_r[1] + s_r[2] + s_r[3]) * (1.0f / 154.0f);
                out[1] =  s_k[0] + s_k[1] + s_k[2] + s_k[3];
                out[2] =  s_n[0] + s_n[1] + s_n[2] + s_n[3];
            }
        }
    } else {
        if (threadIdx.x == 0) {
            atomicAdd(&out[0], (s_r[0] + s_r[1] + s_r[2] + s_r[3]) * (1.0f / 154.0f));
            atomicAdd(&out[1],  s_k[0] + s_k[1] + s_k[2] + s_k[3]);
            atomicAdd(&out[2],  s_n[0] + s_n[1] + s_n[2] + s_n[3]);
        }
    }
}

extern "C" void kernel_launch(void* const* d_in, const int* in_sizes, int n_in,
                              void* d_out, int out_size, void* d_ws, size_t ws_size,
                              hipStream_t stream) {
    const float* recon_l = (const float*)d_in[0];
    const float* recon_r = (const float*)d_in[1];
    const float* kld_l   = (const float*)d_in[2];
    const float* kld_r   = (const float*)d_in[3];
    const int*   lr      = (const int*)d_in[4];
    const int*   fp      = (const int*)d_in[5];
    float* out = (float*)d_out;

    const bool use_ws = (d_ws != nullptr) &&
                        (ws_size >= (size_t)(3 * BLOCKS + 1) * sizeof(float));
    float* ws = use_ws ? (float*)d_ws : nullptr;
    unsigned int* counter = use_ws ? (unsigned int*)((float*)d_ws + 3 * BLOCKS)
                                   : nullptr;

    if (use_ws) {
        init_ws_kernel<<<1, 64, 0, stream>>>(counter);
    } else {
        zero_out_kernel<<<1, 64, 0, stream>>>(out);
    }
    pose_partial_kernel<<<BLOCKS, THREADS, 0, stream>>>(
        recon_l, recon_r, kld_l, kld_r, lr, fp, ws, counter, out);
}

// Round 8
// 165.266 us; speedup vs baseline: 3.6402x; 3.6402x over previous
//
#include <hip/hip_runtime.h>

// Pose_Loss: B=65536 rows, D=154 cols, 4 fp32 arrays + 2 int mask arrays.
// out[0] = (dot(use_l, rowsum(recon_l)) + dot(use_r, rowsum(recon_r))) / 154
// out[1] =  dot(use_l, rowsum(KLD_l))   + dot(use_r, rowsum(KLD_r))
// out[2] =  sum(use_l) + sum(use_r)   (integer count, stored as float)
//
// R8 = R6 structure (PROVEN: 165 us bench, main kernel ~38 us) + ballot
// count from R7. R7's last-block-done reduction is REVERTED: its
// __threadfence release/acquire forces L2 writeback+invalidate per block
// (per-XCD L2 non-coherence), 9856 blocks -> ~20k L2 flushes -> main
// kernel 475 us. A separate 1-block reduce launch is 100x cheaper.
//  - nt loads (confirmed R6): HBM-miss fetches don't allocate in L3, so
//    they don't evict the harness restore's dirty lines -> no hidden
//    in-window writeback. Main kernel 56.5 -> ~38 us.
//  - D = 154 = 2*77 => a float2 half never straddles a row. float4 chunk i
//    covers halves 2i, 2i+1 with rows (2i)/77, (2i+1)/77 (branch-free).
//  - N4 = 2,523,136 = 9856 blocks * 256 threads exactly, VGPR 16.
//  - count via __ballot/popcll in blocks 0..255 only: kills one of three
//    shuffle chains in every block's tail.

#define BB 65536
#define DD 154
#define N4 (BB * DD / 4)        // 2,523,136
#define BLOCKS 9856             // N4 / 256
#define THREADS 256
#define CNT_BLOCKS (BB / THREADS)  // 256

typedef float nt_float4 __attribute__((ext_vector_type(4)));

__global__ void zero_out_kernel(float* __restrict__ out) {
    if (threadIdx.x < 3) out[threadIdx.x] = 0.0f;
}

__device__ __forceinline__ float2 wpair(int l, int f) {
    const bool valid = (f != -1);
    float2 w;
    w.x = (valid && ((l == 0) || (l == 2))) ? 1.0f : 0.0f;
    w.y = (valid && ((l == 1) || (l == 2))) ? 1.0f : 0.0f;
    return w;
}

// ws layout: ws[0..BLOCKS) = recon partials, [B..2B) = kld, [2B..3B) = cnt
__global__ __launch_bounds__(THREADS) void pose_partial_kernel(
    const float* __restrict__ recon_l, const float* __restrict__ recon_r,
    const float* __restrict__ kld_l,   const float* __restrict__ kld_r,
    const int* __restrict__ lr,        const int* __restrict__ fp,
    float* __restrict__ ws,            float* __restrict__ out)
{
    const nt_float4* __restrict__ rl4 = (const nt_float4*)recon_l;
    const nt_float4* __restrict__ rr4 = (const nt_float4*)recon_r;
    const nt_float4* __restrict__ kl4 = (const nt_float4*)kld_l;
    const nt_float4* __restrict__ kr4 = (const nt_float4*)kld_r;

    const int i = blockIdx.x * THREADS + threadIdx.x;   // float4 chunk index
    const int h = 2 * i;
    const int r0 = h / 77;            // row of elements 4i, 4i+1
    const int r1 = (h + 1) / 77;      // row of elements 4i+2, 4i+3

    // non-temporal streaming loads: read once, do not allocate in cache
    const nt_float4 a = __builtin_nontemporal_load(&rl4[i]);
    const nt_float4 b = __builtin_nontemporal_load(&rr4[i]);
    const nt_float4 c = __builtin_nontemporal_load(&kl4[i]);
    const nt_float4 d = __builtin_nontemporal_load(&kr4[i]);

    // weight lookups stay cached (tiny, heavily reused across lanes)
    const float2 w0 = wpair(lr[r0], fp[r0]);
    const float2 w1 = wpair(lr[r1], fp[r1]);

    float acc_recon = w0.x * (a.x + a.y) + w1.x * (a.z + a.w)
                    + w0.y * (b.x + b.y) + w1.y * (b.z + b.w);
    float acc_kld   = w0.x * (c.x + c.y) + w1.x * (c.z + c.w)
                    + w0.y * (d.x + d.y) + w1.y * (d.z + d.w);

    // mask count via ballot popcount: blocks 0..255 own rows i < BB.
    float n_wave = 0.0f;
    if (blockIdx.x < CNT_BLOCKS) {
        const float2 w = wpair(lr[i], fp[i]);
        n_wave = (float)(__popcll(__ballot(w.x != 0.0f)) +
                         __popcll(__ballot(w.y != 0.0f)));
    }

#pragma unroll
    for (int off = 32; off > 0; off >>= 1) {
        acc_recon += __shfl_down(acc_recon, off, 64);
        acc_kld   += __shfl_down(acc_kld,   off, 64);
    }

    __shared__ float s_r[4], s_k[4], s_n[4];
    const int wave = threadIdx.x >> 6;
    const int lane = threadIdx.x & 63;
    if (lane == 0) {
        s_r[wave] = acc_recon;
        s_k[wave] = acc_kld;
        s_n[wave] = n_wave;
    }
    __syncthreads();

    if (threadIdx.x == 0) {
        const float r = s_r[0] + s_r[1] + s_r[2] + s_r[3];
        const float k = s_k[0] + s_k[1] + s_k[2] + s_k[3];
        const float n = s_n[0] + s_n[1] + s_n[2] + s_n[3];
        if (ws != nullptr) {
            ws[blockIdx.x]              = r;
            ws[BLOCKS + blockIdx.x]     = k;
            ws[2 * BLOCKS + blockIdx.x] = n;
        } else {
            atomicAdd(&out[0], r * (1.0f / 154.0f));
            atomicAdd(&out[1], k);
            atomicAdd(&out[2], n);
        }
    }
}

__global__ __launch_bounds__(1024) void final_reduce_kernel(
    const float* __restrict__ ws, float* __restrict__ out)
{
    float r = 0.0f, k = 0.0f, n = 0.0f;
    for (int i = threadIdx.x; i < BLOCKS; i += 1024) {
        r += ws[i];
        k += ws[BLOCKS + i];
        n += ws[2 * BLOCKS + i];
    }
#pragma unroll
    for (int off = 32; off > 0; off >>= 1) {
        r += __shfl_down(r, off, 64);
        k += __shfl_down(k, off, 64);
        n += __shfl_down(n, off, 64);
    }
    __shared__ float s_r[16], s_k[16], s_n[16];
    const int wave = threadIdx.x >> 6;
    const int lane = threadIdx.x & 63;
    if (lane == 0) { s_r[wave] = r; s_k[wave] = k; s_n[wave] = n; }
    __syncthreads();
    if (threadIdx.x == 0) {
        float rr = 0.0f, kk = 0.0f, nn = 0.0f;
#pragma unroll
        for (int w = 0; w < 16; ++w) { rr += s_r[w]; kk += s_k[w]; nn += s_n[w]; }
        out[0] = rr * (1.0f / 154.0f);
        out[1] = kk;
        out[2] = nn;
    }
}

extern "C" void kernel_launch(void* const* d_in, const int* in_sizes, int n_in,
                              void* d_out, int out_size, void* d_ws, size_t ws_size,
                              hipStream_t stream) {
    const float* recon_l = (const float*)d_in[0];
    const float* recon_r = (const float*)d_in[1];
    const float* kld_l   = (const float*)d_in[2];
    const float* kld_r   = (const float*)d_in[3];
    const int*   lr      = (const int*)d_in[4];
    const int*   fp      = (const int*)d_in[5];
    float* out = (float*)d_out;

    const bool use_ws = (d_ws != nullptr) &&
                        (ws_size >= (size_t)(3 * BLOCKS) * sizeof(float));
    float* ws = use_ws ? (float*)d_ws : nullptr;

    if (!use_ws) {
        zero_out_kernel<<<1, 64, 0, stream>>>(out);
    }
    pose_partial_kernel<<<BLOCKS, THREADS, 0, stream>>>(
        recon_l, recon_r, kld_l, kld_r, lr, fp, ws, out);
    if (use_ws) {
        final_reduce_kernel<<<1, 1024, 0, stream>>>(ws, out);
    }
}